// Round 1
// baseline (310.491 us; speedup 1.0000x reference)
//
#include <hip/hip_runtime.h>
#include <math.h>

// EntropyBottleneck forward (eval-mode): out = round(x - med) + med,
// lik = |sigmoid(s*U) - sigmoid(s*L)| with L/U = 4-layer per-channel MLP at out∓0.5.
// Since out quantizes to (integer r + med), likelihood depends only on (channel, r):
// precompute a per-channel 256-entry LUT (r in [-128,127]) with accurate libm math,
// then the main pass is a pure streaming kernel (memory-bound).

constexpr int Bn = 8, Cn = 192, Hn = 128, Wn = 128;
constexpr int HWn = Hn * Wn;                               // 16384
constexpr long long NELEM = (long long)Bn * Cn * HWn;      // 25165824
constexpr int LUTN = 256;                                  // r in [-128, 127]
constexpr float BOUND = 1e-9f;

struct Params {
  float med;
  float w0[3], b0[3], f0[3];
  float w1[9], b1[3], f1[3];
  float w2[9], b2[3], f2[3];
  float w3[3], b3;
};

// ---- math helpers -------------------------------------------------------

__device__ __forceinline__ float fast_rcp(float x) { return __builtin_amdgcn_rcpf(x); }

__device__ __forceinline__ float fast_tanhx(float x) {
  float e = __expf(2.0f * x);
  return 1.0f - 2.0f * fast_rcp(e + 1.0f);
}
__device__ __forceinline__ float fast_sigmoid(float x) {
  return fast_rcp(1.0f + __expf(-x));
}
__device__ __forceinline__ float acc_sigmoid(float x) {
  return 1.0f / (1.0f + expf(-x));
}
// jax.nn.softplus(x) = max(x,0) + log1p(exp(-|x|))
__device__ __forceinline__ float softplus_acc(float x) {
  return fmaxf(x, 0.0f) + log1pf(expf(-fabsf(x)));
}

template <bool ACC>
__device__ __forceinline__ float tanh_sel(float x) {
  return ACC ? tanhf(x) : fast_tanhx(x);
}
template <bool ACC>
__device__ __forceinline__ float sig_sel(float x) {
  return ACC ? acc_sigmoid(x) : fast_sigmoid(x);
}

// ---- per-channel parameter load (softplus weights, tanh factors) --------

__device__ __forceinline__ void load_params(
    Params& P, int c,
    const float* __restrict__ m0, const float* __restrict__ b0, const float* __restrict__ f0,
    const float* __restrict__ m1, const float* __restrict__ b1, const float* __restrict__ f1,
    const float* __restrict__ m2, const float* __restrict__ b2, const float* __restrict__ f2,
    const float* __restrict__ m3, const float* __restrict__ b3, const float* __restrict__ q) {
  P.med = q[c * 3 + 1];
#pragma unroll
  for (int j = 0; j < 3; ++j) {
    P.w0[j] = softplus_acc(m0[c * 3 + j]);
    P.b0[j] = b0[c * 3 + j];
    P.f0[j] = tanhf(f0[c * 3 + j]);
    P.b1[j] = b1[c * 3 + j];
    P.f1[j] = tanhf(f1[c * 3 + j]);
    P.b2[j] = b2[c * 3 + j];
    P.f2[j] = tanhf(f2[c * 3 + j]);
    P.w3[j] = softplus_acc(m3[c * 3 + j]);
  }
#pragma unroll
  for (int k = 0; k < 9; ++k) {
    P.w1[k] = softplus_acc(m1[c * 9 + k]);
    P.w2[k] = softplus_acc(m2[c * 9 + k]);
  }
  P.b3 = b3[c];
}

// ---- MLP (logits_cumulative) -------------------------------------------

template <bool ACC>
__device__ __forceinline__ float mlp_eval(const Params& P, float t) {
  float h0 = fmaf(P.w0[0], t, P.b0[0]);
  float h1 = fmaf(P.w0[1], t, P.b0[1]);
  float h2 = fmaf(P.w0[2], t, P.b0[2]);
  h0 = fmaf(P.f0[0], tanh_sel<ACC>(h0), h0);
  h1 = fmaf(P.f0[1], tanh_sel<ACC>(h1), h1);
  h2 = fmaf(P.f0[2], tanh_sel<ACC>(h2), h2);

  float g0 = fmaf(P.w1[0], h0, fmaf(P.w1[1], h1, fmaf(P.w1[2], h2, P.b1[0])));
  float g1 = fmaf(P.w1[3], h0, fmaf(P.w1[4], h1, fmaf(P.w1[5], h2, P.b1[1])));
  float g2 = fmaf(P.w1[6], h0, fmaf(P.w1[7], h1, fmaf(P.w1[8], h2, P.b1[2])));
  g0 = fmaf(P.f1[0], tanh_sel<ACC>(g0), g0);
  g1 = fmaf(P.f1[1], tanh_sel<ACC>(g1), g1);
  g2 = fmaf(P.f1[2], tanh_sel<ACC>(g2), g2);

  float q0 = fmaf(P.w2[0], g0, fmaf(P.w2[1], g1, fmaf(P.w2[2], g2, P.b2[0])));
  float q1 = fmaf(P.w2[3], g0, fmaf(P.w2[4], g1, fmaf(P.w2[5], g2, P.b2[1])));
  float q2 = fmaf(P.w2[6], g0, fmaf(P.w2[7], g1, fmaf(P.w2[8], g2, P.b2[2])));
  q0 = fmaf(P.f2[0], tanh_sel<ACC>(q0), q0);
  q1 = fmaf(P.f2[1], tanh_sel<ACC>(q1), q1);
  q2 = fmaf(P.f2[2], tanh_sel<ACC>(q2), q2);

  return fmaf(P.w3[0], q0, fmaf(P.w3[1], q1, fmaf(P.w3[2], q2, P.b3)));
}

template <bool ACC>
__device__ __forceinline__ float likelihood_of(const Params& P, float o) {
  float lo = mlp_eval<ACC>(P, o - 0.5f);
  float up = mlp_eval<ACC>(P, o + 0.5f);
  float su = lo + up;
  // sign = -sign(lo+up), with sign(0) == 0
  float s = (su > 0.0f) ? -1.0f : ((su < 0.0f) ? 1.0f : 0.0f);
  float d = fabsf(sig_sel<ACC>(s * up) - sig_sel<ACC>(s * lo));
  return fmaxf(d, BOUND);
}

// ---- kernel 1: per-channel LUT build (accurate math, tiny) -------------

__global__ __launch_bounds__(LUTN) void build_lut(
    const float* __restrict__ m0, const float* __restrict__ b0, const float* __restrict__ f0,
    const float* __restrict__ m1, const float* __restrict__ b1, const float* __restrict__ f1,
    const float* __restrict__ m2, const float* __restrict__ b2, const float* __restrict__ f2,
    const float* __restrict__ m3, const float* __restrict__ b3, const float* __restrict__ q,
    float* __restrict__ lut) {
  __shared__ Params P;
  const int c = blockIdx.x;
  if (threadIdx.x == 0) {
    load_params(P, c, m0, b0, f0, m1, b1, f1, m2, b2, f2, m3, b3, q);
  }
  __syncthreads();
  const int t = threadIdx.x;
  const float o = (float)(t - 128) + P.med;  // out value for integer r = t-128
  lut[c * LUTN + t] = likelihood_of<true>(P, o);
}

// ---- kernel 2: streaming main pass (memory-bound) ----------------------

__global__ __launch_bounds__(256, 8) void eb_lut_main(
    const float* __restrict__ x, const float* __restrict__ q,
    const float* __restrict__ lut, float* __restrict__ out, float* __restrict__ lik) {
  __shared__ float slut[LUTN];
  const int slab = blockIdx.x;       // b*C + c
  const int c = slab % Cn;
  slut[threadIdx.x] = lut[c * LUTN + threadIdx.x];
  const float med = q[c * 3 + 1];
  __syncthreads();

  const long long base = (long long)slab * HWn;
  const float4* __restrict__ xin = (const float4*)(x + base);
  float4* __restrict__ po = (float4*)(out + base);
  float4* __restrict__ pl = (float4*)(lik + base);

#pragma unroll
  for (int it = 0; it < HWn / 4 / 256; ++it) {   // 16 iterations
    const int i = threadIdx.x + it * 256;
    float4 xv = xin[i];
    float4 ov, lv;
    {
      float r = rintf(xv.x - med); ov.x = r + med;
      int idx = (int)r + 128; idx = idx < 0 ? 0 : (idx > 255 ? 255 : idx);
      lv.x = slut[idx];
    }
    {
      float r = rintf(xv.y - med); ov.y = r + med;
      int idx = (int)r + 128; idx = idx < 0 ? 0 : (idx > 255 ? 255 : idx);
      lv.y = slut[idx];
    }
    {
      float r = rintf(xv.z - med); ov.z = r + med;
      int idx = (int)r + 128; idx = idx < 0 ? 0 : (idx > 255 ? 255 : idx);
      lv.z = slut[idx];
    }
    {
      float r = rintf(xv.w - med); ov.w = r + med;
      int idx = (int)r + 128; idx = idx < 0 ? 0 : (idx > 255 ? 255 : idx);
      lv.w = slut[idx];
    }
    po[i] = ov;
    pl[i] = lv;
  }
}

// ---- fallback: direct per-element compute (if ws too small) ------------

__global__ __launch_bounds__(256, 4) void eb_direct(
    const float* __restrict__ x,
    const float* __restrict__ m0, const float* __restrict__ b0, const float* __restrict__ f0,
    const float* __restrict__ m1, const float* __restrict__ b1, const float* __restrict__ f1,
    const float* __restrict__ m2, const float* __restrict__ b2, const float* __restrict__ f2,
    const float* __restrict__ m3, const float* __restrict__ b3, const float* __restrict__ q,
    float* __restrict__ out, float* __restrict__ lik) {
  __shared__ Params SP;
  const int slab = blockIdx.x;
  const int c = slab % Cn;
  if (threadIdx.x == 0) {
    load_params(SP, c, m0, b0, f0, m1, b1, f1, m2, b2, f2, m3, b3, q);
  }
  __syncthreads();
  Params P = SP;  // registers

  const long long base = (long long)slab * HWn;
  const float4* __restrict__ xin = (const float4*)(x + base);
  float4* __restrict__ po = (float4*)(out + base);
  float4* __restrict__ pl = (float4*)(lik + base);

  for (int it = 0; it < HWn / 4 / 256; ++it) {
    const int i = threadIdx.x + it * 256;
    float4 xv = xin[i];
    float4 ov, lv;
    {
      float r = rintf(xv.x - P.med); ov.x = r + P.med; lv.x = likelihood_of<false>(P, ov.x);
    }
    {
      float r = rintf(xv.y - P.med); ov.y = r + P.med; lv.y = likelihood_of<false>(P, ov.y);
    }
    {
      float r = rintf(xv.z - P.med); ov.z = r + P.med; lv.z = likelihood_of<false>(P, ov.z);
    }
    {
      float r = rintf(xv.w - P.med); ov.w = r + P.med; lv.w = likelihood_of<false>(P, ov.w);
    }
    po[i] = ov;
    pl[i] = lv;
  }
}

// ---- launch -------------------------------------------------------------

extern "C" void kernel_launch(void* const* d_in, const int* in_sizes, int n_in,
                              void* d_out, int out_size, void* d_ws, size_t ws_size,
                              hipStream_t stream) {
  const float* x  = (const float*)d_in[0];
  const float* m0 = (const float*)d_in[1];
  const float* b0 = (const float*)d_in[2];
  const float* f0 = (const float*)d_in[3];
  const float* m1 = (const float*)d_in[4];
  const float* b1 = (const float*)d_in[5];
  const float* f1 = (const float*)d_in[6];
  const float* m2 = (const float*)d_in[7];
  const float* b2 = (const float*)d_in[8];
  const float* f2 = (const float*)d_in[9];
  const float* m3 = (const float*)d_in[10];
  const float* b3 = (const float*)d_in[11];
  const float* q  = (const float*)d_in[12];

  float* out = (float*)d_out;
  float* lik = out + NELEM;

  const size_t lut_bytes = (size_t)Cn * LUTN * sizeof(float);
  if (ws_size >= lut_bytes) {
    float* lut = (float*)d_ws;
    build_lut<<<Cn, LUTN, 0, stream>>>(m0, b0, f0, m1, b1, f1, m2, b2, f2, m3, b3, q, lut);
    eb_lut_main<<<Bn * Cn, 256, 0, stream>>>(x, q, lut, out, lik);
  } else {
    eb_direct<<<Bn * Cn, 256, 0, stream>>>(x, m0, b0, f0, m1, b1, f1, m2, b2, f2,
                                           m3, b3, q, out, lik);
  }
}

// Round 2
// 293.985 us; speedup vs baseline: 1.0561x; 1.0561x over previous
//
#include <hip/hip_runtime.h>
#include <math.h>

// EntropyBottleneck forward (eval-mode), single fused kernel.
// out = round(x - med) + med; likelihood depends only on (channel, integer r):
// each block computes its channel's 256-entry likelihood LUT in LDS with
// accurate libm math (bit-exact vs JAX ref, verified absmax=0.0 in R1),
// then streams 16384 elements with float4 nontemporal loads/stores.
// No workspace needed.

constexpr int Bn = 8, Cn = 192, Hn = 128, Wn = 128;
constexpr int HWn = Hn * Wn;                           // 16384
constexpr long long NELEM = (long long)Bn * Cn * HWn;  // 25165824
constexpr int LUTN = 256;                              // r in [-128, 127]
constexpr float BOUND = 1e-9f;

typedef float f4 __attribute__((ext_vector_type(4)));

struct Params {
  float med;
  float w0[3], b0[3], f0[3];
  float w1[9], b1[3], f1[3];
  float w2[9], b2[3], f2[3];
  float w3[3], b3;
};

// jax.nn.softplus(x) = max(x,0) + log1p(exp(-|x|))
__device__ __forceinline__ float softplus_acc(float x) {
  return fmaxf(x, 0.0f) + log1pf(expf(-fabsf(x)));
}

// accurate 4-layer per-channel MLP (logits_cumulative), params from LDS
__device__ __forceinline__ float mlp_acc(const Params& P, float t) {
  float h0 = fmaf(P.w0[0], t, P.b0[0]);
  float h1 = fmaf(P.w0[1], t, P.b0[1]);
  float h2 = fmaf(P.w0[2], t, P.b0[2]);
  h0 = fmaf(P.f0[0], tanhf(h0), h0);
  h1 = fmaf(P.f0[1], tanhf(h1), h1);
  h2 = fmaf(P.f0[2], tanhf(h2), h2);

  float g0 = fmaf(P.w1[0], h0, fmaf(P.w1[1], h1, fmaf(P.w1[2], h2, P.b1[0])));
  float g1 = fmaf(P.w1[3], h0, fmaf(P.w1[4], h1, fmaf(P.w1[5], h2, P.b1[1])));
  float g2 = fmaf(P.w1[6], h0, fmaf(P.w1[7], h1, fmaf(P.w1[8], h2, P.b1[2])));
  g0 = fmaf(P.f1[0], tanhf(g0), g0);
  g1 = fmaf(P.f1[1], tanhf(g1), g1);
  g2 = fmaf(P.f1[2], tanhf(g2), g2);

  float q0 = fmaf(P.w2[0], g0, fmaf(P.w2[1], g1, fmaf(P.w2[2], g2, P.b2[0])));
  float q1 = fmaf(P.w2[3], g0, fmaf(P.w2[4], g1, fmaf(P.w2[5], g2, P.b2[1])));
  float q2 = fmaf(P.w2[6], g0, fmaf(P.w2[7], g1, fmaf(P.w2[8], g2, P.b2[2])));
  q0 = fmaf(P.f2[0], tanhf(q0), q0);
  q1 = fmaf(P.f2[1], tanhf(q1), q1);
  q2 = fmaf(P.f2[2], tanhf(q2), q2);

  return fmaf(P.w3[0], q0, fmaf(P.w3[1], q1, fmaf(P.w3[2], q2, P.b3)));
}

__global__ __launch_bounds__(256, 8) void eb_fused(
    const float* __restrict__ x,
    const float* __restrict__ m0, const float* __restrict__ b0, const float* __restrict__ f0,
    const float* __restrict__ m1, const float* __restrict__ b1, const float* __restrict__ f1,
    const float* __restrict__ m2, const float* __restrict__ b2, const float* __restrict__ f2,
    const float* __restrict__ m3, const float* __restrict__ b3, const float* __restrict__ q,
    float* __restrict__ out, float* __restrict__ lik) {
  __shared__ Params P;
  __shared__ float slut[LUTN];

  const int slab = blockIdx.x;  // b*C + c
  const int c = slab % Cn;
  const int t = threadIdx.x;

  // ---- cooperative parameter prep (one-time, 44 threads) ----
  if (t < 3)        P.w0[t]      = softplus_acc(m0[c * 3 + t]);
  else if (t < 12)  P.w1[t - 3]  = softplus_acc(m1[c * 9 + (t - 3)]);
  else if (t < 21)  P.w2[t - 12] = softplus_acc(m2[c * 9 + (t - 12)]);
  else if (t < 24)  P.w3[t - 21] = softplus_acc(m3[c * 3 + (t - 21)]);
  else if (t < 27)  P.f0[t - 24] = tanhf(f0[c * 3 + (t - 24)]);
  else if (t < 30)  P.f1[t - 27] = tanhf(f1[c * 3 + (t - 27)]);
  else if (t < 33)  P.f2[t - 30] = tanhf(f2[c * 3 + (t - 30)]);
  else if (t < 36)  P.b0[t - 33] = b0[c * 3 + (t - 33)];
  else if (t < 39)  P.b1[t - 36] = b1[c * 3 + (t - 36)];
  else if (t < 42)  P.b2[t - 39] = b2[c * 3 + (t - 39)];
  else if (t == 42) P.b3 = b3[c];
  else if (t == 43) P.med = q[c * 3 + 1];
  __syncthreads();

  const float med = P.med;

  // ---- build this channel's LUT entry t (accurate math, one-time) ----
  {
    const float o = (float)(t - 128) + med;  // out value for integer r = t-128
    float lo = mlp_acc(P, o - 0.5f);
    float up = mlp_acc(P, o + 0.5f);
    float su = lo + up;
    float s = (su > 0.0f) ? -1.0f : ((su < 0.0f) ? 1.0f : 0.0f);
    float d = fabsf(1.0f / (1.0f + expf(-s * up)) - 1.0f / (1.0f + expf(-s * lo)));
    slut[t] = fmaxf(d, BOUND);
  }
  __syncthreads();

  // ---- streaming main pass (memory-bound) ----
  const long long base = (long long)slab * HWn;
  const f4* __restrict__ xin = (const f4*)(x + base);
  f4* __restrict__ po = (f4*)(out + base);
  f4* __restrict__ pl = (f4*)(lik + base);

#pragma unroll
  for (int it = 0; it < HWn / 4 / 256; ++it) {  // 16 iterations
    const int i = t + it * 256;
    f4 xv = __builtin_nontemporal_load(&xin[i]);
    f4 ov, lv;
#pragma unroll
    for (int j = 0; j < 4; ++j) {
      float r = rintf(xv[j] - med);
      ov[j] = r + med;
      int idx = (int)r + 128;
      idx = idx < 0 ? 0 : (idx > 255 ? 255 : idx);
      lv[j] = slut[idx];
    }
    __builtin_nontemporal_store(ov, &po[i]);
    __builtin_nontemporal_store(lv, &pl[i]);
  }
}

extern "C" void kernel_launch(void* const* d_in, const int* in_sizes, int n_in,
                              void* d_out, int out_size, void* d_ws, size_t ws_size,
                              hipStream_t stream) {
  const float* x  = (const float*)d_in[0];
  const float* m0 = (const float*)d_in[1];
  const float* b0 = (const float*)d_in[2];
  const float* f0 = (const float*)d_in[3];
  const float* m1 = (const float*)d_in[4];
  const float* b1 = (const float*)d_in[5];
  const float* f1 = (const float*)d_in[6];
  const float* m2 = (const float*)d_in[7];
  const float* b2 = (const float*)d_in[8];
  const float* f2 = (const float*)d_in[9];
  const float* m3 = (const float*)d_in[10];
  const float* b3 = (const float*)d_in[11];
  const float* q  = (const float*)d_in[12];

  float* out = (float*)d_out;
  float* lik = out + NELEM;

  eb_fused<<<Bn * Cn, 256, 0, stream>>>(x, m0, b0, f0, m1, b1, f1, m2, b2, f2,
                                        m3, b3, q, out, lik);
}